// Round 8
// baseline (298.468 us; speedup 1.0000x reference)
//
#include <hip/hip_runtime.h>
#include <math.h>

#define D_MELS  80
#define T_DIM   4000
#define F4_ROW  20     // float4 per row
#define NQ      10
#define NTHR    256
#define WPB     (NTHR / 64)   // waves per block = 4
#define RPW     16            // rows per wave-iteration
#define LDSROWS (RPW + 2)     // 18: rows 0,1 = halo (base-2, base-1)
#define MAXB    4096

typedef float f4 __attribute__((ext_vector_type(4)));

__device__ __forceinline__ f4 ntload(const f4* p) {
    return __builtin_nontemporal_load(p);
}

// compiler-level fence: DS pipe is in-order per wave; stop LLVM from
// reordering cross-lane LDS write->read. Free at runtime.
#define WAVE_FENCE() do { __asm__ volatile("" ::: "memory"); \
                          __builtin_amdgcn_wave_barrier();    \
                          __asm__ volatile("" ::: "memory"); } while (0)

// quantities: 0=l1 1=band 2=diff2 3=tgt2 4=energy 5=mask 6=delta 7=dmask 8=delta2 9=d2mask

__global__ __launch_bounds__(NTHR, 5) void mel_loss_main(
    const float* __restrict__ pred, const float* __restrict__ tgt,
    const float* __restrict__ mask, const float* __restrict__ w,
    float* __restrict__ partial, int BT, int total_waves)
{
    const int tid  = threadIdx.x;
    const int lane = tid & 63;
    const int qtr  = lane & 3;       // quarter: float4s qtr+4k, k=0..4
    const int rw   = lane >> 2;      // row within stripe, 0..15
    const int wid  = tid >> 6;
    const int gwave = blockIdx.x * WPB + wid;

    const f4* p4 = (const f4*)pred;
    const f4* q4 = (const f4*)tgt;

    __shared__ f4    wvb[F4_ROW];                  // band weights, 320 B
    __shared__ f4    ebuf[WPB][LDSROWS * F4_ROW];  // 23040 B
    __shared__ float red[WPB][NQ];
    f4* my = ebuf[wid];

    if (tid < F4_ROW) wvb[tid] = ((const f4*)w)[tid];
    __syncthreads();

    float v_l1 = 0.f, v_band = 0.f, v_diff2 = 0.f, v_tgt2 = 0.f, v_energy = 0.f;
    float v_m = 0.f, v_d = 0.f, v_dm = 0.f, v_d2 = 0.f, v_d2m = 0.f;

    const int stride_rows = total_waves * RPW;

    for (int base = gwave * RPW; base < BT; base += stride_rows) {
        int r = base + rw;
        bool active = (r < BT);
        int rc = active ? r : (BT - 1);
        int t = rc % T_DIM;

        const f4* pr = p4 + (size_t)rc * F4_ROW + qtr;
        const f4* qr = q4 + (size_t)rc * F4_ROW + qtr;

        // mask loads early (tiny, mostly L2-hit)
        float mt = active ? mask[rc] : 0.f;
        float m1 = (active && t >= 1) ? mask[rc - 1] : 0.f;
        float m2 = (active && t >= 2) ? mask[rc - 2] : 0.f;

        // ---- halo first (8/64 lanes) so its latency overlaps the primary ----
        if (rw <= 1) {
            bool hvalid = active && (t >= 2);
            const f4* ph = pr - 2 * F4_ROW;
            const f4* qh = qr - 2 * F4_ROW;
            #pragma unroll
            for (int k = 0; k < 5; ++k) {
                f4 he = (f4)(0.f);
                if (hvalid) he = ph[4 * k] - qh[4 * k];
                my[rw * F4_ROW + qtr + 4 * k] = he;
            }
        }

        // ---- primary cluster: all 10 independent nt loads in flight ----
        f4 P[5], Q[5];
        #pragma unroll
        for (int k = 0; k < 5; ++k) P[k] = ntload(pr + 4 * k);
        #pragma unroll
        for (int k = 0; k < 5; ++k) Q[k] = ntload(qr + 4 * k);

        // ---- pointwise terms + stash e in LDS ----
        float l1r = 0.f, bandr = 0.f, sqr = 0.f, t2r = 0.f, er = 0.f;
        #pragma unroll
        for (int k = 0; k < 5; ++k) {
            f4 e = P[k] - Q[k];
            f4 wv = wvb[qtr + 4 * k];
            float a0 = fabsf(e.x), a1 = fabsf(e.y),
                  a2 = fabsf(e.z), a3 = fabsf(e.w);
            l1r   += a0 + a1 + a2 + a3;
            bandr += a0 * wv.x + a1 * wv.y + a2 * wv.z + a3 * wv.w;
            sqr   += e.x * e.x + e.y * e.y + e.z * e.z + e.w * e.w;
            t2r   += Q[k].x * Q[k].x + Q[k].y * Q[k].y
                   + Q[k].z * Q[k].z + Q[k].w * Q[k].w;
            er    += e.x + e.y + e.z + e.w;
            my[(rw + 2) * F4_ROW + qtr + 4 * k] = e;
        }

        // writes must be visible before cross-lane reads
        WAVE_FENCE();

        // ---- temporal terms from LDS (wave-private, no block barrier) ----
        float dmv  = mt * m1;
        float d2mv = dmv * m2;

        float dr = 0.f, d2r = 0.f;
        #pragma unroll
        for (int k = 0; k < 5; ++k) {
            f4 e = my[(rw + 2) * F4_ROW + qtr + 4 * k];
            f4 f = my[(rw + 1) * F4_ROW + qtr + 4 * k];
            f4 g = my[rw * F4_ROW + qtr + 4 * k];
            dr  += fabsf(e.x - f.x) + fabsf(e.y - f.y)
                 + fabsf(e.z - f.z) + fabsf(e.w - f.w);
            d2r += fabsf(e.x - 2.f * f.x + g.x) + fabsf(e.y - 2.f * f.y + g.y)
                 + fabsf(e.z - 2.f * f.z + g.z) + fabsf(e.w - 2.f * f.w + g.w);
        }

        v_l1    += l1r * mt;
        v_band  += bandr * mt;
        v_diff2 += sqr * mt;
        v_tgt2  += t2r * mt;
        v_d     += dr * dmv;
        v_d2    += d2r * d2mv;

        er += __shfl_xor(er, 1, 64);
        er += __shfl_xor(er, 2, 64);
        if (qtr == 0) {
            v_energy += fabsf(er) * mt;
            v_m   += mt;
            v_dm  += dmv;
            v_d2m += d2mv;
        }

        // WAR: next iteration overwrites rows just read
        WAVE_FENCE();
    }

    // ---- final reduction: wave shuffle -> LDS -> per-block store (no atomics) ----
    float vals[NQ] = {v_l1, v_band, v_diff2, v_tgt2, v_energy,
                      v_m, v_d, v_dm, v_d2, v_d2m};
    #pragma unroll
    for (int q = 0; q < NQ; ++q) {
        float v = vals[q];
        #pragma unroll
        for (int off = 32; off > 0; off >>= 1)
            v += __shfl_down(v, off, 64);
        vals[q] = v;
    }
    if (lane == 0) {
        #pragma unroll
        for (int q = 0; q < NQ; ++q) red[wid][q] = vals[q];
    }
    __syncthreads();
    if (tid < NQ) {
        float s = 0.f;
        #pragma unroll
        for (int wv2 = 0; wv2 < WPB; ++wv2) s += red[wv2][tid];
        partial[tid * MAXB + blockIdx.x] = s;
    }
}

__global__ __launch_bounds__(640) void mel_loss_finalize(
    const float* __restrict__ partial, const float* __restrict__ w,
    float* __restrict__ out, int nblk)
{
    const int tid = threadIdx.x;
    const int wv  = tid >> 6;        // quantity index 0..9
    const int lane = tid & 63;
    __shared__ float fin[NQ];

    float s = 0.f;
    for (int i = lane; i < nblk; i += 64) s += partial[wv * MAXB + i];
    #pragma unroll
    for (int off = 32; off > 0; off >>= 1) s += __shfl_down(s, off, 64);
    if (lane == 0) fin[wv] = s;
    __syncthreads();

    if (tid == 0) {
        float l1s = fin[0], bands = fin[1], diff2 = fin[2], tgt2 = fin[3];
        float energys = fin[4], ms = fin[5], ds = fin[6], dms = fin[7];
        float d2s = fin[8], d2ms = fin[9];

        float wsum = 0.f;
        for (int d = 0; d < D_MELS; ++d) wsum += w[d];
        float wmean = wsum / (float)D_MELS;

        float n1  = fmaxf(ms   * (float)D_MELS, 1.f);
        float nd  = fmaxf(dms  * (float)D_MELS, 1.f);
        float nd2 = fmaxf(d2ms * (float)D_MELS, 1.f);

        float l1_loss     = l1s / n1;
        float delta_loss  = ds / nd;
        float delta2_loss = d2s / nd2;
        float sc_num = sqrtf(diff2 / n1);
        float sc_den = fmaxf(sqrtf(tgt2 / n1), 1e-8f);
        float sc_loss = sc_num / sc_den;
        float band_loss = (bands / n1) / wmean;
        float energy_loss = (energys / (float)D_MELS) / fmaxf(ms, 1.f);

        out[0] = 1.0f * l1_loss + 0.5f * delta_loss + 0.25f * delta2_loss
               + 0.5f * sc_loss + 1.0f * band_loss + 0.5f * energy_loss;
    }
}

extern "C" void kernel_launch(void* const* d_in, const int* in_sizes, int n_in,
                              void* d_out, int out_size, void* d_ws, size_t ws_size,
                              hipStream_t stream) {
    const float* pred = (const float*)d_in[0];
    const float* tgt  = (const float*)d_in[1];
    const float* mask = (const float*)d_in[2];
    const float* w    = (const float*)d_in[3];
    int BT = in_sizes[2];                 // B*T = 256000
    float* partial = (float*)d_ws;        // NQ * MAXB floats = 160 KB

    // one 16-row stripe per wave: grid 4000 blocks, no grid-stride reuse
    int rows_per_block = WPB * RPW;                          // 64
    int grid = (BT + rows_per_block - 1) / rows_per_block;   // 4000
    if (grid > MAXB) grid = MAXB;
    if (grid < 1) grid = 1;
    int total_waves = grid * WPB;

    mel_loss_main<<<grid, NTHR, 0, stream>>>(pred, tgt, mask, w, partial, BT, total_waves);
    mel_loss_finalize<<<1, 640, 0, stream>>>(partial, w, (float*)d_out, grid);
}